// Round 16
// baseline (225.058 us; speedup 1.0000x reference)
//
#include <hip/hip_runtime.h>
#include <hip/hip_bf16.h>

// ---------------------------------------------------------------------------
// 2-layer GAT (8 heads x 16 hidden, in=128, N=50k, E=1.6M) on gfx950.
//   Dispatch DAG (7 launches):
//     fused_pre  : bhist || wtrans(W0) || wtrans(W1)
//     bscan1     : per-bucket cross-block offsets + totals
//     scatter    : bucket-group edges (bucket bases from btot, in-LDS scan)
//     fused_mid  : bucket_csr || gemm0  (csr hides under the layer-0 GEMM)
//     agg0 -> gemm1 -> agg1
//   - GEMM reads Wt fragments DIRECTLY from global (32KB, L2-resident):
//     LDS 48->16KB lifts occupancy 3->~6 blocks/CU; staging at HBM rate.
//   - Aggregate (R8/R12 form — measured floor ~70us, fabric/latency-bound):
//     one wave per dst node, single-pass no-max softmax, exp staged once per
//     (edge,head), readlane SGPR-base 256B gathers. col ushort; H/x1 bf16.
// ---------------------------------------------------------------------------

#define HEADS 8
#define HID 16
#define HF 128
#define SLOPE 0.2f

#define BSHIFT 8
#define BRANGE 256            // nodes per bucket
#define CHUNK 4096            // edges per scatter/hist block

typedef __attribute__((ext_vector_type(8))) short bf16x8;
typedef __attribute__((ext_vector_type(4))) float f32x4;

static __device__ __forceinline__ unsigned int f2bf(float f) {
    unsigned int u = __float_as_uint(f);
    u += 0x7fffu + ((u >> 16) & 1u);      // round-to-nearest-even
    return u >> 16;
}

// ----------------------- GEMM body (device inline) -------------------------
// 256 thr, tile 64 rows x 128 cols; D = Wt-frag * X-frag (16x16x32 bf16).
// X staged in LDS (16KB, swizzled); Wt fragments read directly from global
// (Wtb is 32KB row-major [c][k], L2-resident; 16B-aligned per-lane slices).

template <bool XBF16>
static __device__ __forceinline__ void gemm_body(
    int blk, unsigned short* xs,
    const void* __restrict__ Xv, const unsigned short* __restrict__ Wtb,
    const float* __restrict__ AL, const float* __restrict__ AR,
    unsigned short* __restrict__ Hb, float* __restrict__ EL,
    float* __restrict__ ER, int n) {
    int t = threadIdx.x;
    int row0 = blk * 64;

    {
        int r = t >> 2;
        int gr = row0 + r;
        unsigned int rowbase = r * 256;
        unsigned int sw = (r & 7) << 4;
        if (XBF16) {
            unsigned int kb0 = (t & 3) * 64;
            const char* src = (const char*)Xv + (size_t)gr * 256 + kb0;
            #pragma unroll
            for (int i = 0; i < 4; ++i) {
                int4 v = (gr < n) ? *(const int4*)(src + i * 16)
                                  : make_int4(0, 0, 0, 0);
                *(int4*)((char*)xs + rowbase + ((kb0 + i * 16) ^ sw)) = v;
            }
        } else {
            int k0 = (t & 3) * 32;
            float4 f[8];
            if (gr < n) {
                const float4* p = (const float4*)((const float*)Xv + (size_t)gr * HF + k0);
                #pragma unroll
                for (int i = 0; i < 8; ++i) f[i] = p[i];
            } else {
                #pragma unroll
                for (int i = 0; i < 8; ++i) f[i] = make_float4(0.f, 0.f, 0.f, 0.f);
            }
            #pragma unroll
            for (int g2 = 0; g2 < 4; ++g2) {
                float4 a = f[g2 * 2], b = f[g2 * 2 + 1];
                int4 pk;
                pk.x = (int)(f2bf(a.x) | (f2bf(a.y) << 16));
                pk.y = (int)(f2bf(a.z) | (f2bf(a.w) << 16));
                pk.z = (int)(f2bf(b.x) | (f2bf(b.y) << 16));
                pk.w = (int)(f2bf(b.z) | (f2bf(b.w) << 16));
                unsigned int addr = rowbase + ((unsigned)((k0 + g2 * 8) * 2) ^ sw);
                *(int4*)((char*)xs + addr) = pk;
            }
        }
    }
    __syncthreads();

    int wv = t >> 6;
    int l = t & 63;
    int lr = l & 15;
    int g = l >> 4;

    bf16x8 bfr[4];
    {
        int r = wv * 16 + lr;
        unsigned int rowbase = r * 256;
        unsigned int sw = (r & 7) << 4;
        #pragma unroll
        for (int s = 0; s < 4; ++s) {
            unsigned int kbyte = (unsigned)((s * 32 + g * 8) * 2);
            bfr[s] = *(bf16x8*)((char*)xs + rowbase + (kbyte ^ sw));
        }
    }

    f32x4 acc[8];
    #pragma unroll
    for (int ct = 0; ct < 8; ++ct) acc[ct] = (f32x4){0.f, 0.f, 0.f, 0.f};

    #pragma unroll
    for (int ct = 0; ct < 8; ++ct) {
        int c = ct * 16 + lr;
        const unsigned short* wrow = Wtb + (size_t)c * HF + g * 8;
        #pragma unroll
        for (int s = 0; s < 4; ++s) {
            bf16x8 af = *(const bf16x8*)(wrow + s * 32);
            acc[ct] = __builtin_amdgcn_mfma_f32_16x16x32_bf16(af, bfr[s], acc[ct], 0, 0, 0);
        }
    }

    int grow = row0 + wv * 16 + lr;
    bool valid = grow < n;

    if (valid) {
        #pragma unroll
        for (int ct = 0; ct < 8; ++ct) {
            ushort4 hb4 = make_ushort4(
                (unsigned short)f2bf(acc[ct][0]), (unsigned short)f2bf(acc[ct][1]),
                (unsigned short)f2bf(acc[ct][2]), (unsigned short)f2bf(acc[ct][3]));
            *(ushort4*)(Hb + (size_t)grow * HF + ct * 16 + g * 4) = hb4;
        }
    }

    #pragma unroll
    for (int ct = 0; ct < 8; ++ct) {
        float e1 = 0.f, e2 = 0.f;
        #pragma unroll
        for (int rg = 0; rg < 4; ++rg) {
            float alv = AL[ct * 16 + g * 4 + rg];
            float arv = AR[ct * 16 + g * 4 + rg];
            e1 += acc[ct][rg] * alv;
            e2 += acc[ct][rg] * arv;
        }
        e1 += __shfl_xor(e1, 16); e1 += __shfl_xor(e1, 32);
        e2 += __shfl_xor(e2, 16); e2 += __shfl_xor(e2, 32);
        if (g == 0 && valid) {
            EL[grow * HEADS + ct] = e1;
            ER[grow * HEADS + ct] = e2;
        }
    }
}

// -------------------- wtrans body (device inline, 256 thr) -----------------

static __device__ __forceinline__ void wtrans_body(
    int blk, const float* __restrict__ W, unsigned short* __restrict__ Wtb) {
    int gid = blk * 256 + threadIdx.x;
    int c = gid >> 3;
    int k0 = (gid & 7) * 16;
    #pragma unroll
    for (int q = 0; q < 4; ++q) {
        int k = k0 + q * 4;
        ushort4 o = make_ushort4(
            (unsigned short)f2bf(W[(k + 0) * HF + c]),
            (unsigned short)f2bf(W[(k + 1) * HF + c]),
            (unsigned short)f2bf(W[(k + 2) * HF + c]),
            (unsigned short)f2bf(W[(k + 3) * HF + c]));
        *(ushort4*)(Wtb + (size_t)c * HF + k) = o;
    }
}

// ------------------ csr body (device inline, 256 thr) ----------------------

static __device__ __forceinline__ void csr_body(
    int b, char* ldsc, const int* __restrict__ stage, const int* __restrict__ btot,
    int* __restrict__ rowptr, unsigned short* __restrict__ col,
    int N, int nb, int E) {
    int* hist  = (int*)ldsc;          // 256
    int* lscan = hist + 256;          // 256
    int* lcur  = lscan + 256;         // 256
    int* sb    = lcur + 256;          // 256
    int t = threadIdx.x;
    sb[t] = (t < nb) ? btot[t] : 0;
    hist[t] = 0;
    __syncthreads();
    #pragma unroll
    for (int off = 1; off < 256; off <<= 1) {
        int v = (t >= off) ? sb[t - off] : 0;
        __syncthreads();
        sb[t] += v;
        __syncthreads();
    }
    int e0 = (b == 0) ? 0 : sb[b - 1];
    int e1 = sb[b];
    if (b == 0 && t == 0) rowptr[N] = E;

    for (int i = e0 + t; i < e1; i += 256)
        atomicAdd(&hist[(stage[i] >> 16) & (BRANGE - 1)], 1);
    __syncthreads();
    lscan[t] = hist[t];
    __syncthreads();
    #pragma unroll
    for (int off = 1; off < 256; off <<= 1) {
        int v = (t >= off) ? lscan[t - off] : 0;
        __syncthreads();
        lscan[t] += v;
        __syncthreads();
    }
    int ex = (t == 0) ? 0 : lscan[t - 1];
    __syncthreads();
    lcur[t] = ex;
    int node = (b << BSHIFT) + t;
    if (node < N) rowptr[node] = e0 + ex;
    __syncthreads();
    for (int i = e0 + t; i < e1; i += 256) {
        int p = stage[i];
        int pos = e0 + atomicAdd(&lcur[(p >> 16) & (BRANGE - 1)], 1);
        col[pos] = (unsigned short)(p & 0xFFFF);
    }
}

// ---------------- fused_pre: bhist || wtrans(W0) || wtrans(W1) -------------

__global__ __launch_bounds__(256) void fused_pre_kernel(
    const int* __restrict__ edst, int* __restrict__ bhistT, int E, int nb, int nblk,
    const float* __restrict__ W0, unsigned short* __restrict__ wtb0,
    const float* __restrict__ W1, unsigned short* __restrict__ wtb1) {
    __shared__ int h[BRANGE];
    int b = blockIdx.x;
    int t = threadIdx.x;
    if (b < nblk) {
        h[t] = 0;
        __syncthreads();
        int base = b * CHUNK;
        int end = base + CHUNK; if (end > E) end = E;
        for (int i = base + t; i < end; i += 256)
            atomicAdd(&h[edst[i] >> BSHIFT], 1);
        __syncthreads();
        if (t < nb) bhistT[(size_t)t * nblk + b] = h[t];
    } else if (b < nblk + 4) {
        wtrans_body(b - nblk, W0, wtb0);
    } else {
        wtrans_body(b - nblk - 4, W1, wtb1);
    }
}

// per bucket: exclusive scan over blocks -> boffT[bucket][block]; total -> btot
__global__ __launch_bounds__(64) void bscan1_kernel(
    const int* __restrict__ bhistT, int* __restrict__ boffT,
    int* __restrict__ btot, int nblk) {
    int b = blockIdx.x;
    int l = threadIdx.x;
    int carry = 0;
    for (int c0 = 0; c0 < nblk; c0 += 64) {
        int blk = c0 + l;
        int v = (blk < nblk) ? bhistT[(size_t)b * nblk + blk] : 0;
        int x = v;
        #pragma unroll
        for (int off = 1; off < 64; off <<= 1) {
            int y = __shfl_up(x, off, 64);
            if (l >= off) x += y;
        }
        if (blk < nblk) boffT[(size_t)b * nblk + blk] = carry + x - v;
        carry += __shfl(x, 63);
    }
    if (l == 0) btot[b] = carry;
}

// bucket-group edges into stage; bucket bases derived in-LDS from btot
__global__ __launch_bounds__(512) void bucket_scatter_kernel(
    const int* __restrict__ src, const int* __restrict__ dst,
    const int* __restrict__ bhistT, const int* __restrict__ boffT,
    const int* __restrict__ btot, int* __restrict__ stage,
    int E, int nb, int nblk) {
    __shared__ int lscan[BRANGE];
    __shared__ int lcur[BRANGE];
    __shared__ int gbase[BRANGE];
    __shared__ int sb[BRANGE];
    __shared__ int sstage[CHUNK];
    int t = threadIdx.x;
    int blk = blockIdx.x;
    int base = blk * CHUNK;
    int end = base + CHUNK; if (end > E) end = E;

    if (t < 256) {
        lscan[t] = (t < nb) ? bhistT[(size_t)t * nblk + blk] : 0;
        sb[t] = (t < nb) ? btot[t] : 0;
    }
    __syncthreads();
    #pragma unroll
    for (int off = 1; off < 256; off <<= 1) {
        int v = 0, u = 0;
        if (t < 256 && t >= off) { v = lscan[t - off]; u = sb[t - off]; }
        __syncthreads();
        if (t < 256) { lscan[t] += v; sb[t] += u; }
        __syncthreads();
    }
    int ex = 0;
    if (t < 256) ex = (t == 0) ? 0 : lscan[t - 1];
    __syncthreads();
    if (t < 256) {
        lcur[t] = ex;
        lscan[t] = ex;
        if (t < nb) {
            int bb = (t == 0) ? 0 : sb[t - 1];
            gbase[t] = bb + boffT[(size_t)t * nblk + blk];
        }
    }
    __syncthreads();

    for (int i = base + t; i < end; i += 512) {
        int d = dst[i];
        int b = d >> BSHIFT;
        int pos = atomicAdd(&lcur[b], 1);
        sstage[pos] = (src[i] & 0xFFFF) | ((d & (BRANGE - 1)) << 16) | (b << 24);
    }
    __syncthreads();

    int total = end - base;
    for (int i = t; i < total; i += 512) {
        int p = sstage[i];
        int b = ((unsigned)p) >> 24;
        int gpos = gbase[b] + (i - lscan[b]);
        stage[gpos] = p;
    }
}

// ---------------- fused_mid: bucket_csr || gemm0 ---------------------------
// blocks [0,nCsr): csr ; [nCsr, nCsr+gGemm): gemm layer 0. LDS 16KB union.

__global__ __launch_bounds__(256) void fused_mid_kernel(
    const int* __restrict__ stage, const int* __restrict__ btot,
    int* __restrict__ rowptr, unsigned short* __restrict__ col,
    int N, int nb, int E, int nCsr,
    const float* __restrict__ X, const unsigned short* __restrict__ wtb0,
    const float* __restrict__ AL, const float* __restrict__ AR,
    unsigned short* __restrict__ Hb, float* __restrict__ EL,
    float* __restrict__ ER) {
    __shared__ __align__(16) unsigned char lds[16 * 1024];
    int b = blockIdx.x;
    if (b < nCsr) {
        csr_body(b, (char*)lds, stage, btot, rowptr, col, N, nb, E);
    } else {
        gemm_body<false>(b - nCsr, (unsigned short*)lds,
                         X, wtb0, AL, AR, Hb, EL, ER, N);
    }
}

// ------------------------- standalone gemm (layer 1) -----------------------

template <bool XBF16>
__global__ __launch_bounds__(256) void gemm_mfma_kernel(
    const void* __restrict__ Xv, const unsigned short* __restrict__ Wtb,
    const float* __restrict__ AL, const float* __restrict__ AR,
    unsigned short* __restrict__ Hb, float* __restrict__ EL,
    float* __restrict__ ER, int n) {
    __shared__ __align__(16) unsigned short xs[64 * HF];
    gemm_body<XBF16>(blockIdx.x, xs, Xv, Wtb, AL, AR, Hb, EL, ER, n);
}

// --------------------------- softmax-aggregate ------------------------------

template <bool OBF16>
__global__ __launch_bounds__(256) void gat_aggregate_kernel(
    const unsigned int* __restrict__ HbU,   // bf16x2 view of Hb: [N][64]
    const float* __restrict__ EL, const float* __restrict__ ER,
    const int* __restrict__ rowptr, const unsigned short* __restrict__ col,
    void* __restrict__ OUT, int n) {
    int wid = (int)((blockIdx.x * blockDim.x + threadIdx.x) >> 6);
    if (wid >= n) return;
    int lane = threadIdx.x & 63;
    int s0 = rowptr[wid], s1 = rowptr[wid + 1];
    if (s1 == s0) {
        if (OBF16) ((unsigned int*)OUT)[(size_t)wid * 64 + lane] = 0u;
        else ((float2*)OUT)[(size_t)wid * 64 + lane] = make_float2(0.f, 0.f);
        return;
    }

    int h = lane & 7;
    int j = lane >> 3;
    int hC = lane >> 3;
    float er_h = ER[wid * HEADS + h];

    float accx = 0.f, accy = 0.f;
    float dpart = 0.f;

    for (int base = s0; base < s1; base += 8) {
        int i = base + j;
        int icl = i < s1 ? i : s1 - 1;
        int sj = (int)col[icl];
        float e = EL[sj * HEADS + h] + er_h;
        e = fmaxf(e, SLOPE * e);
        float w = __expf(e);
        if (i >= s1) w = 0.f;
        dpart += w;

        if (base + 8 <= s1) {
            #pragma unroll
            for (int jj = 0; jj < 8; ++jj) {
                float wC = __shfl(w, jj * 8 + hC);
                int s = __builtin_amdgcn_readlane(sj, jj * 8);
                unsigned int pv = HbU[(size_t)s * 64 + lane];
                accx += wC * __uint_as_float(pv << 16);
                accy += wC * __uint_as_float(pv & 0xffff0000u);
            }
        } else {
            int ne = s1 - base;
            for (int jj = 0; jj < ne; ++jj) {
                float wC = __shfl(w, jj * 8 + hC);
                int s = __builtin_amdgcn_readlane(sj, jj * 8);
                unsigned int pv = HbU[(size_t)s * 64 + lane];
                accx += wC * __uint_as_float(pv << 16);
                accy += wC * __uint_as_float(pv & 0xffff0000u);
            }
        }
    }

    dpart += __shfl_xor(dpart, 8);
    dpart += __shfl_xor(dpart, 16);
    dpart += __shfl_xor(dpart, 32);
    float rC = 1.f / __shfl(dpart, hC);

    if (OBF16) {
        unsigned int o = f2bf(accx * rC) | (f2bf(accy * rC) << 16);
        ((unsigned int*)OUT)[(size_t)wid * 64 + lane] = o;
    } else {
        ((float2*)OUT)[(size_t)wid * 64 + lane] = make_float2(accx * rC, accy * rC);
    }
}

// ------------------------------- launch -------------------------------------

extern "C" void kernel_launch(void* const* d_in, const int* in_sizes, int n_in,
                              void* d_out, int out_size, void* d_ws, size_t ws_size,
                              hipStream_t stream) {
    const float* feat = (const float*)d_in[0];
    const int*   esrc = (const int*)d_in[1];
    const int*   edst = (const int*)d_in[2];
    const float* W0   = (const float*)d_in[3];
    const float* al0  = (const float*)d_in[4];
    const float* ar0  = (const float*)d_in[5];
    const float* W1   = (const float*)d_in[6];
    const float* al1  = (const float*)d_in[7];
    const float* ar1  = (const float*)d_in[8];
    float* out = (float*)d_out;

    const int N = in_sizes[0] / HF;     // 50000
    const int E = in_sizes[1];          // 1600000
    const int nb = (N + BRANGE - 1) >> BSHIFT;        // 196
    const int nblk = (E + CHUNK - 1) / CHUNK;         // 391

    char* w = (char*)d_ws;
    auto alloc = [&](size_t bytes) -> void* {
        void* p = (void*)w;
        w += (bytes + 255) & ~(size_t)255;
        return p;
    };
    unsigned short* hb   = (unsigned short*)alloc((size_t)N * HF * 2);  // bf16 H
    unsigned short* x1b  = (unsigned short*)alloc((size_t)N * HF * 2);  // bf16 x1
    float* el_buf = (float*)alloc((size_t)N * HEADS * 4);
    float* er_buf = (float*)alloc((size_t)N * HEADS * 4);
    int*   rowptr = (int*)alloc((size_t)(N + 1) * 4);
    unsigned short* col = (unsigned short*)alloc((size_t)E * 2);
    int*   bhistT = (int*)alloc((size_t)nb * nblk * 4);
    int*   boffT  = (int*)alloc((size_t)nb * nblk * 4);
    int*   btot   = (int*)alloc((size_t)nb * 4);
    unsigned short* wtb0 = (unsigned short*)alloc((size_t)HF * HF * 2);
    unsigned short* wtb1 = (unsigned short*)alloc((size_t)HF * HF * 2);
    int*   stage  = (int*)alloc((size_t)E * 4);

    int gGemm = (N + 63) / 64;          // 782
    int gAgg  = (N * 64 + 255) / 256;

    // ---- fused_pre: bhist || wtrans(W0) || wtrans(W1) ----
    fused_pre_kernel<<<nblk + 8, 256, 0, stream>>>(edst, bhistT, E, nb, nblk,
                                                   W0, wtb0, W1, wtb1);
    // ---- per-bucket offsets ----
    bscan1_kernel<<<nb, 64, 0, stream>>>(bhistT, boffT, btot, nblk);
    // ---- bucket-group edges ----
    bucket_scatter_kernel<<<nblk, 512, 0, stream>>>(esrc, edst, bhistT, boffT,
                                                    btot, stage, E, nb, nblk);
    // ---- fused_mid: csr || gemm0 ----
    fused_mid_kernel<<<nb + gGemm, 256, 0, stream>>>(
        stage, btot, rowptr, col, N, nb, E, nb,
        feat, wtb0, al0, ar0, hb, el_buf, er_buf);

    // ---- layer 0 aggregate ----
    gat_aggregate_kernel<true><<<gAgg, 256, 0, stream>>>(
        (const unsigned int*)hb, el_buf, er_buf, rowptr, col, x1b, N);

    // ---- layer 1 ----
    gemm_mfma_kernel<true><<<gGemm, 256, 0, stream>>>(x1b, wtb1, al1, ar1,
                                                      hb, el_buf, er_buf, N);
    gat_aggregate_kernel<false><<<gAgg, 256, 0, stream>>>(
        (const unsigned int*)hb, el_buf, er_buf, rowptr, col, out, N);
}

// Round 17
// 214.356 us; speedup vs baseline: 1.0499x; 1.0499x over previous
//
#include <hip/hip_runtime.h>
#include <hip/hip_bf16.h>

// ---------------------------------------------------------------------------
// 2-layer GAT (8 heads x 16 hidden, in=128, N=50k, E=1.6M) on gfx950.
//   Dispatch DAG (6 launches):
//     fused_pre     : bhist || wtrans(W0) || wtrans(W1)
//     bscan1        : per-bucket cross-block offsets + totals
//     fused_scatter : bucket-scatter || gemm0 blocks [0,352)
//     fused_mid     : bucket_csr || gemm0 blocks [352,782)
//     agg0 -> gemm1 -> agg1
//   - GEMM: R15 form (X + Wt staged in LDS, 48KB, XOR-swizzled) — R16 showed
//     global-W MFMA operands regress (VMEM latency in inner loop).
//   - Aggregate (R8/R12 form — measured floor ~70us, latency-bound):
//     one wave per dst node, single-pass no-max softmax, exp staged once per
//     (edge,head), readlane SGPR-base 256B gathers. col ushort; H/x1 bf16.
// ---------------------------------------------------------------------------

#define HEADS 8
#define HID 16
#define HF 128
#define SLOPE 0.2f

#define BSHIFT 8
#define BRANGE 256            // nodes per bucket
#define CHUNK 4096            // edges per scatter/hist block

typedef __attribute__((ext_vector_type(8))) short bf16x8;
typedef __attribute__((ext_vector_type(4))) float f32x4;

static __device__ __forceinline__ unsigned int f2bf(float f) {
    unsigned int u = __float_as_uint(f);
    u += 0x7fffu + ((u >> 16) & 1u);      // round-to-nearest-even
    return u >> 16;
}

// ----------------------- GEMM body (device inline) -------------------------
// 256 thr, tile 64 rows x 128 cols; D = Wt-frag * X-frag (16x16x32 bf16).
// X (16KB) and Wt (32KB) staged in LDS, XOR-swizzled (byte ^= (row&7)<<4).

template <bool XBF16>
static __device__ __forceinline__ void gemm_body(
    int blk, unsigned short* xs, unsigned short* ws,
    const void* __restrict__ Xv, const unsigned short* __restrict__ Wtb,
    const float* __restrict__ AL, const float* __restrict__ AR,
    unsigned short* __restrict__ Hb, float* __restrict__ EL,
    float* __restrict__ ER, int n) {
    int t = threadIdx.x;
    int row0 = blk * 64;

    {
        int r = t >> 2;
        int gr = row0 + r;
        unsigned int rowbase = r * 256;
        unsigned int sw = (r & 7) << 4;
        if (XBF16) {
            unsigned int kb0 = (t & 3) * 64;
            const char* src = (const char*)Xv + (size_t)gr * 256 + kb0;
            #pragma unroll
            for (int i = 0; i < 4; ++i) {
                int4 v = (gr < n) ? *(const int4*)(src + i * 16)
                                  : make_int4(0, 0, 0, 0);
                *(int4*)((char*)xs + rowbase + ((kb0 + i * 16) ^ sw)) = v;
            }
        } else {
            int k0 = (t & 3) * 32;
            float4 f[8];
            if (gr < n) {
                const float4* p = (const float4*)((const float*)Xv + (size_t)gr * HF + k0);
                #pragma unroll
                for (int i = 0; i < 8; ++i) f[i] = p[i];
            } else {
                #pragma unroll
                for (int i = 0; i < 8; ++i) f[i] = make_float4(0.f, 0.f, 0.f, 0.f);
            }
            #pragma unroll
            for (int g2 = 0; g2 < 4; ++g2) {
                float4 a = f[g2 * 2], b = f[g2 * 2 + 1];
                int4 pk;
                pk.x = (int)(f2bf(a.x) | (f2bf(a.y) << 16));
                pk.y = (int)(f2bf(a.z) | (f2bf(a.w) << 16));
                pk.z = (int)(f2bf(b.x) | (f2bf(b.y) << 16));
                pk.w = (int)(f2bf(b.z) | (f2bf(b.w) << 16));
                unsigned int addr = rowbase + ((unsigned)((k0 + g2 * 8) * 2) ^ sw);
                *(int4*)((char*)xs + addr) = pk;
            }
        }
    }
    {
        int c = t >> 1;
        unsigned int kb0 = (t & 1) * 128;
        const int4* src = (const int4*)((const char*)Wtb + (size_t)c * 256 + kb0);
        unsigned int sw = (c & 7) << 4;
        #pragma unroll
        for (int i = 0; i < 8; ++i) {
            int4 v = src[i];
            unsigned int addr = c * 256 + ((kb0 + i * 16) ^ sw);
            *(int4*)((char*)ws + addr) = v;
        }
    }
    __syncthreads();

    int wv = t >> 6;
    int l = t & 63;
    int lr = l & 15;
    int g = l >> 4;

    bf16x8 bfr[4];
    {
        int r = wv * 16 + lr;
        unsigned int rowbase = r * 256;
        unsigned int sw = (r & 7) << 4;
        #pragma unroll
        for (int s = 0; s < 4; ++s) {
            unsigned int kbyte = (unsigned)((s * 32 + g * 8) * 2);
            bfr[s] = *(bf16x8*)((char*)xs + rowbase + (kbyte ^ sw));
        }
    }

    f32x4 acc[8];
    #pragma unroll
    for (int ct = 0; ct < 8; ++ct) acc[ct] = (f32x4){0.f, 0.f, 0.f, 0.f};

    #pragma unroll
    for (int ct = 0; ct < 8; ++ct) {
        int c = ct * 16 + lr;
        unsigned int rowbase = c * 256;
        unsigned int sw = (c & 7) << 4;
        #pragma unroll
        for (int s = 0; s < 4; ++s) {
            unsigned int kbyte = (unsigned)((s * 32 + g * 8) * 2);
            bf16x8 af = *(bf16x8*)((char*)ws + rowbase + (kbyte ^ sw));
            acc[ct] = __builtin_amdgcn_mfma_f32_16x16x32_bf16(af, bfr[s], acc[ct], 0, 0, 0);
        }
    }

    int grow = row0 + wv * 16 + lr;
    bool valid = grow < n;

    if (valid) {
        #pragma unroll
        for (int ct = 0; ct < 8; ++ct) {
            ushort4 hb4 = make_ushort4(
                (unsigned short)f2bf(acc[ct][0]), (unsigned short)f2bf(acc[ct][1]),
                (unsigned short)f2bf(acc[ct][2]), (unsigned short)f2bf(acc[ct][3]));
            *(ushort4*)(Hb + (size_t)grow * HF + ct * 16 + g * 4) = hb4;
        }
    }

    #pragma unroll
    for (int ct = 0; ct < 8; ++ct) {
        float e1 = 0.f, e2 = 0.f;
        #pragma unroll
        for (int rg = 0; rg < 4; ++rg) {
            float alv = AL[ct * 16 + g * 4 + rg];
            float arv = AR[ct * 16 + g * 4 + rg];
            e1 += acc[ct][rg] * alv;
            e2 += acc[ct][rg] * arv;
        }
        e1 += __shfl_xor(e1, 16); e1 += __shfl_xor(e1, 32);
        e2 += __shfl_xor(e2, 16); e2 += __shfl_xor(e2, 32);
        if (g == 0 && valid) {
            EL[grow * HEADS + ct] = e1;
            ER[grow * HEADS + ct] = e2;
        }
    }
}

// -------------------- wtrans body (device inline, 256 thr) -----------------

static __device__ __forceinline__ void wtrans_body(
    int blk, const float* __restrict__ W, unsigned short* __restrict__ Wtb) {
    int gid = blk * 256 + threadIdx.x;
    int c = gid >> 3;
    int k0 = (gid & 7) * 16;
    #pragma unroll
    for (int q = 0; q < 4; ++q) {
        int k = k0 + q * 4;
        ushort4 o = make_ushort4(
            (unsigned short)f2bf(W[(k + 0) * HF + c]),
            (unsigned short)f2bf(W[(k + 1) * HF + c]),
            (unsigned short)f2bf(W[(k + 2) * HF + c]),
            (unsigned short)f2bf(W[(k + 3) * HF + c]));
        *(ushort4*)(Wtb + (size_t)c * HF + k) = o;
    }
}

// ---------------- scatter body (device inline, 256 thr) --------------------
// Bucket-group CHUNK edges into stage; bucket bases from btot (in-LDS scan).

static __device__ __forceinline__ void scatter_body(
    int blk, char* ldsc,
    const int* __restrict__ src, const int* __restrict__ dst,
    const int* __restrict__ bhistT, const int* __restrict__ boffT,
    const int* __restrict__ btot, int* __restrict__ stage,
    int E, int nb, int nblk) {
    int* lscan  = (int*)ldsc;         // 256
    int* lcur   = lscan + 256;        // 256
    int* gbase  = lcur + 256;         // 256
    int* sb     = gbase + 256;        // 256
    int* sstage = sb + 256;           // 4096
    int t = threadIdx.x;
    int base = blk * CHUNK;
    int end = base + CHUNK; if (end > E) end = E;

    lscan[t] = (t < nb) ? bhistT[(size_t)t * nblk + blk] : 0;
    sb[t]    = (t < nb) ? btot[t] : 0;
    __syncthreads();
    #pragma unroll
    for (int off = 1; off < 256; off <<= 1) {
        int v = (t >= off) ? lscan[t - off] : 0;
        int u = (t >= off) ? sb[t - off] : 0;
        __syncthreads();
        lscan[t] += v; sb[t] += u;
        __syncthreads();
    }
    int ex = (t == 0) ? 0 : lscan[t - 1];
    int bb = (t == 0) ? 0 : sb[t - 1];
    __syncthreads();
    lcur[t] = ex;
    lscan[t] = ex;
    if (t < nb) gbase[t] = bb + boffT[(size_t)t * nblk + blk];
    __syncthreads();

    for (int i = base + t; i < end; i += 256) {
        int d = dst[i];
        int b = d >> BSHIFT;
        int pos = atomicAdd(&lcur[b], 1);
        sstage[pos] = (src[i] & 0xFFFF) | ((d & (BRANGE - 1)) << 16) | (b << 24);
    }
    __syncthreads();

    int total = end - base;
    for (int i = t; i < total; i += 256) {
        int p = sstage[i];
        int b = ((unsigned)p) >> 24;
        stage[gbase[b] + (i - lscan[b])] = p;
    }
}

// ------------------ csr body (device inline, 256 thr) ----------------------

static __device__ __forceinline__ void csr_body(
    int b, char* ldsc, const int* __restrict__ stage, const int* __restrict__ btot,
    int* __restrict__ rowptr, unsigned short* __restrict__ col,
    int N, int nb, int E) {
    int* hist  = (int*)ldsc;          // 256
    int* lscan = hist + 256;          // 256
    int* lcur  = lscan + 256;         // 256
    int* sb    = lcur + 256;          // 256
    int t = threadIdx.x;
    sb[t] = (t < nb) ? btot[t] : 0;
    hist[t] = 0;
    __syncthreads();
    #pragma unroll
    for (int off = 1; off < 256; off <<= 1) {
        int v = (t >= off) ? sb[t - off] : 0;
        __syncthreads();
        sb[t] += v;
        __syncthreads();
    }
    int e0 = (b == 0) ? 0 : sb[b - 1];
    int e1 = sb[b];
    if (b == 0 && t == 0) rowptr[N] = E;

    for (int i = e0 + t; i < e1; i += 256)
        atomicAdd(&hist[(stage[i] >> 16) & (BRANGE - 1)], 1);
    __syncthreads();
    lscan[t] = hist[t];
    __syncthreads();
    #pragma unroll
    for (int off = 1; off < 256; off <<= 1) {
        int v = (t >= off) ? lscan[t - off] : 0;
        __syncthreads();
        lscan[t] += v;
        __syncthreads();
    }
    int ex = (t == 0) ? 0 : lscan[t - 1];
    __syncthreads();
    lcur[t] = ex;
    int node = (b << BSHIFT) + t;
    if (node < N) rowptr[node] = e0 + ex;
    __syncthreads();
    for (int i = e0 + t; i < e1; i += 256) {
        int p = stage[i];
        int pos = e0 + atomicAdd(&lcur[(p >> 16) & (BRANGE - 1)], 1);
        col[pos] = (unsigned short)(p & 0xFFFF);
    }
}

// ---------------- fused_pre: bhist || wtrans(W0) || wtrans(W1) -------------

__global__ __launch_bounds__(256) void fused_pre_kernel(
    const int* __restrict__ edst, int* __restrict__ bhistT, int E, int nb, int nblk,
    const float* __restrict__ W0, unsigned short* __restrict__ wtb0,
    const float* __restrict__ W1, unsigned short* __restrict__ wtb1) {
    __shared__ int h[BRANGE];
    int b = blockIdx.x;
    int t = threadIdx.x;
    if (b < nblk) {
        h[t] = 0;
        __syncthreads();
        int base = b * CHUNK;
        int end = base + CHUNK; if (end > E) end = E;
        for (int i = base + t; i < end; i += 256)
            atomicAdd(&h[edst[i] >> BSHIFT], 1);
        __syncthreads();
        if (t < nb) bhistT[(size_t)t * nblk + b] = h[t];
    } else if (b < nblk + 4) {
        wtrans_body(b - nblk, W0, wtb0);
    } else {
        wtrans_body(b - nblk - 4, W1, wtb1);
    }
}

// per bucket: exclusive scan over blocks -> boffT[bucket][block]; total -> btot
__global__ __launch_bounds__(64) void bscan1_kernel(
    const int* __restrict__ bhistT, int* __restrict__ boffT,
    int* __restrict__ btot, int nblk) {
    int b = blockIdx.x;
    int l = threadIdx.x;
    int carry = 0;
    for (int c0 = 0; c0 < nblk; c0 += 64) {
        int blk = c0 + l;
        int v = (blk < nblk) ? bhistT[(size_t)b * nblk + blk] : 0;
        int x = v;
        #pragma unroll
        for (int off = 1; off < 64; off <<= 1) {
            int y = __shfl_up(x, off, 64);
            if (l >= off) x += y;
        }
        if (blk < nblk) boffT[(size_t)b * nblk + blk] = carry + x - v;
        carry += __shfl(x, 63);
    }
    if (l == 0) btot[b] = carry;
}

// ---------------- fused_scatter: scatter || gemm0 [0,gSplit) ---------------

__global__ __launch_bounds__(256) void fused_scatter_kernel(
    const int* __restrict__ src, const int* __restrict__ dst,
    const int* __restrict__ bhistT, const int* __restrict__ boffT,
    const int* __restrict__ btot, int* __restrict__ stage,
    int E, int nb, int nblk,
    const float* __restrict__ X, const unsigned short* __restrict__ wtb0,
    const float* __restrict__ AL, const float* __restrict__ AR,
    unsigned short* __restrict__ Hb, float* __restrict__ EL,
    float* __restrict__ ER, int N) {
    __shared__ __align__(16) unsigned char lds[48 * 1024];
    int b = blockIdx.x;
    if (b < nblk) {
        scatter_body(b, (char*)lds, src, dst, bhistT, boffT, btot, stage, E, nb, nblk);
    } else {
        gemm_body<false>(b - nblk, (unsigned short*)lds,
                         (unsigned short*)(lds + 16384),
                         X, wtb0, AL, AR, Hb, EL, ER, N);
    }
}

// ---------------- fused_mid: bucket_csr || gemm0 [gSplit,782) --------------

__global__ __launch_bounds__(256) void fused_mid_kernel(
    const int* __restrict__ stage, const int* __restrict__ btot,
    int* __restrict__ rowptr, unsigned short* __restrict__ col,
    int N, int nb, int E, int nCsr, int gSplit,
    const float* __restrict__ X, const unsigned short* __restrict__ wtb0,
    const float* __restrict__ AL, const float* __restrict__ AR,
    unsigned short* __restrict__ Hb, float* __restrict__ EL,
    float* __restrict__ ER) {
    __shared__ __align__(16) unsigned char lds[48 * 1024];
    int b = blockIdx.x;
    if (b < nCsr) {
        csr_body(b, (char*)lds, stage, btot, rowptr, col, N, nb, E);
    } else {
        gemm_body<false>(b - nCsr + gSplit, (unsigned short*)lds,
                         (unsigned short*)(lds + 16384),
                         X, wtb0, AL, AR, Hb, EL, ER, N);
    }
}

// ------------------------- standalone gemm (layer 1) -----------------------

template <bool XBF16>
__global__ __launch_bounds__(256) void gemm_mfma_kernel(
    const void* __restrict__ Xv, const unsigned short* __restrict__ Wtb,
    const float* __restrict__ AL, const float* __restrict__ AR,
    unsigned short* __restrict__ Hb, float* __restrict__ EL,
    float* __restrict__ ER, int n) {
    __shared__ __align__(16) unsigned short xs[64 * HF];
    __shared__ __align__(16) unsigned short ws[HF * HF];
    gemm_body<XBF16>(blockIdx.x, xs, ws, Xv, Wtb, AL, AR, Hb, EL, ER, n);
}

// --------------------------- softmax-aggregate ------------------------------

template <bool OBF16>
__global__ __launch_bounds__(256) void gat_aggregate_kernel(
    const unsigned int* __restrict__ HbU,   // bf16x2 view of Hb: [N][64]
    const float* __restrict__ EL, const float* __restrict__ ER,
    const int* __restrict__ rowptr, const unsigned short* __restrict__ col,
    void* __restrict__ OUT, int n) {
    int wid = (int)((blockIdx.x * blockDim.x + threadIdx.x) >> 6);
    if (wid >= n) return;
    int lane = threadIdx.x & 63;
    int s0 = rowptr[wid], s1 = rowptr[wid + 1];
    if (s1 == s0) {
        if (OBF16) ((unsigned int*)OUT)[(size_t)wid * 64 + lane] = 0u;
        else ((float2*)OUT)[(size_t)wid * 64 + lane] = make_float2(0.f, 0.f);
        return;
    }

    int h = lane & 7;
    int j = lane >> 3;
    int hC = lane >> 3;
    float er_h = ER[wid * HEADS + h];

    float accx = 0.f, accy = 0.f;
    float dpart = 0.f;

    for (int base = s0; base < s1; base += 8) {
        int i = base + j;
        int icl = i < s1 ? i : s1 - 1;
        int sj = (int)col[icl];
        float e = EL[sj * HEADS + h] + er_h;
        e = fmaxf(e, SLOPE * e);
        float w = __expf(e);
        if (i >= s1) w = 0.f;
        dpart += w;

        if (base + 8 <= s1) {
            #pragma unroll
            for (int jj = 0; jj < 8; ++jj) {
                float wC = __shfl(w, jj * 8 + hC);
                int s = __builtin_amdgcn_readlane(sj, jj * 8);
                unsigned int pv = HbU[(size_t)s * 64 + lane];
                accx += wC * __uint_as_float(pv << 16);
                accy += wC * __uint_as_float(pv & 0xffff0000u);
            }
        } else {
            int ne = s1 - base;
            for (int jj = 0; jj < ne; ++jj) {
                float wC = __shfl(w, jj * 8 + hC);
                int s = __builtin_amdgcn_readlane(sj, jj * 8);
                unsigned int pv = HbU[(size_t)s * 64 + lane];
                accx += wC * __uint_as_float(pv << 16);
                accy += wC * __uint_as_float(pv & 0xffff0000u);
            }
        }
    }

    dpart += __shfl_xor(dpart, 8);
    dpart += __shfl_xor(dpart, 16);
    dpart += __shfl_xor(dpart, 32);
    float rC = 1.f / __shfl(dpart, hC);

    if (OBF16) {
        unsigned int o = f2bf(accx * rC) | (f2bf(accy * rC) << 16);
        ((unsigned int*)OUT)[(size_t)wid * 64 + lane] = o;
    } else {
        ((float2*)OUT)[(size_t)wid * 64 + lane] = make_float2(accx * rC, accy * rC);
    }
}

// ------------------------------- launch -------------------------------------

extern "C" void kernel_launch(void* const* d_in, const int* in_sizes, int n_in,
                              void* d_out, int out_size, void* d_ws, size_t ws_size,
                              hipStream_t stream) {
    const float* feat = (const float*)d_in[0];
    const int*   esrc = (const int*)d_in[1];
    const int*   edst = (const int*)d_in[2];
    const float* W0   = (const float*)d_in[3];
    const float* al0  = (const float*)d_in[4];
    const float* ar0  = (const float*)d_in[5];
    const float* W1   = (const float*)d_in[6];
    const float* al1  = (const float*)d_in[7];
    const float* ar1  = (const float*)d_in[8];
    float* out = (float*)d_out;

    const int N = in_sizes[0] / HF;     // 50000
    const int E = in_sizes[1];          // 1600000
    const int nb = (N + BRANGE - 1) >> BSHIFT;        // 196
    const int nblk = (E + CHUNK - 1) / CHUNK;         // 391

    char* w = (char*)d_ws;
    auto alloc = [&](size_t bytes) -> void* {
        void* p = (void*)w;
        w += (bytes + 255) & ~(size_t)255;
        return p;
    };
    unsigned short* hb   = (unsigned short*)alloc((size_t)N * HF * 2);  // bf16 H
    unsigned short* x1b  = (unsigned short*)alloc((size_t)N * HF * 2);  // bf16 x1
    float* el_buf = (float*)alloc((size_t)N * HEADS * 4);
    float* er_buf = (float*)alloc((size_t)N * HEADS * 4);
    int*   rowptr = (int*)alloc((size_t)(N + 1) * 4);
    unsigned short* col = (unsigned short*)alloc((size_t)E * 2);
    int*   bhistT = (int*)alloc((size_t)nb * nblk * 4);
    int*   boffT  = (int*)alloc((size_t)nb * nblk * 4);
    int*   btot   = (int*)alloc((size_t)nb * 4);
    unsigned short* wtb0 = (unsigned short*)alloc((size_t)HF * HF * 2);
    unsigned short* wtb1 = (unsigned short*)alloc((size_t)HF * HF * 2);
    int*   stage  = (int*)alloc((size_t)E * 4);

    int gGemm = (N + 63) / 64;          // 782
    int gSplit = 352;                   // gemm0 blocks co-run with scatter
    int gAgg  = (N * 64 + 255) / 256;

    // ---- fused_pre: bhist || wtrans(W0) || wtrans(W1) ----
    fused_pre_kernel<<<nblk + 8, 256, 0, stream>>>(edst, bhistT, E, nb, nblk,
                                                   W0, wtb0, W1, wtb1);
    // ---- per-bucket offsets ----
    bscan1_kernel<<<nb, 64, 0, stream>>>(bhistT, boffT, btot, nblk);
    // ---- fused_scatter: scatter || gemm0 [0,gSplit) ----
    fused_scatter_kernel<<<nblk + gSplit, 256, 0, stream>>>(
        esrc, edst, bhistT, boffT, btot, stage, E, nb, nblk,
        feat, wtb0, al0, ar0, hb, el_buf, er_buf, N);
    // ---- fused_mid: csr || gemm0 [gSplit,gGemm) ----
    fused_mid_kernel<<<nb + (gGemm - gSplit), 256, 0, stream>>>(
        stage, btot, rowptr, col, N, nb, E, nb, gSplit,
        feat, wtb0, al0, ar0, hb, el_buf, er_buf);

    // ---- layer 0 aggregate ----
    gat_aggregate_kernel<true><<<gAgg, 256, 0, stream>>>(
        (const unsigned int*)hb, el_buf, er_buf, rowptr, col, x1b, N);

    // ---- layer 1 ----
    gemm_mfma_kernel<true><<<gGemm, 256, 0, stream>>>(x1b, wtb1, al1, ar1,
                                                      hb, el_buf, er_buf, N);
    gat_aggregate_kernel<false><<<gAgg, 256, 0, stream>>>(
        (const unsigned int*)hb, el_buf, er_buf, rowptr, col, out, N);
}

// Round 18
// 210.953 us; speedup vs baseline: 1.0669x; 1.0161x over previous
//
#include <hip/hip_runtime.h>
#include <hip/hip_bf16.h>

// ---------------------------------------------------------------------------
// 2-layer GAT (8 heads x 16 hidden, in=128, N=50k, E=1.6M) on gfx950.
//   Dispatch DAG (7 launches) — best measured configuration (R15, 211.6us):
//     fused_pre  : bhist || wtrans(W0) || wtrans(W1)
//     bscan1     : per-bucket cross-block offsets + totals
//     scatter    : bucket-group edges (bucket bases from btot, in-LDS scan)
//     fused_mid  : bucket_csr || gemm0  (csr hides under the layer-0 GEMM)
//     agg0 -> gemm1 -> agg1
//   - GEMM: X + Wt staged in LDS (48KB, XOR-swizzled). R16 showed global-W
//     operands regress (VMEM latency in MFMA loop); R7 showed f32-VALU slower.
//   - Aggregate (R8/R12 form — empirical floor ~69us, random-gather
//     fabric-limited; R7/R9/R10/R11 alternatives all slower): one wave per
//     dst node, single-pass no-max softmax (logits O(1) by construction),
//     exp staged once per (edge,head), readlane SGPR-base 256B gathers.
//     col ushort; H/x1 bf16.
// ---------------------------------------------------------------------------

#define HEADS 8
#define HID 16
#define HF 128
#define SLOPE 0.2f

#define BSHIFT 8
#define BRANGE 256            // nodes per bucket
#define CHUNK 4096            // edges per scatter/hist block

typedef __attribute__((ext_vector_type(8))) short bf16x8;
typedef __attribute__((ext_vector_type(4))) float f32x4;

static __device__ __forceinline__ unsigned int f2bf(float f) {
    unsigned int u = __float_as_uint(f);
    u += 0x7fffu + ((u >> 16) & 1u);      // round-to-nearest-even
    return u >> 16;
}

// ----------------------- GEMM body (device inline) -------------------------
// 256 thr, tile 64 rows x 128 cols; D = Wt-frag * X-frag (16x16x32 bf16).
// X (16KB) and Wt (32KB) staged in LDS, XOR-swizzled (byte ^= (row&7)<<4).

template <bool XBF16>
static __device__ __forceinline__ void gemm_body(
    int blk, unsigned short* xs, unsigned short* ws,
    const void* __restrict__ Xv, const unsigned short* __restrict__ Wtb,
    const float* __restrict__ AL, const float* __restrict__ AR,
    unsigned short* __restrict__ Hb, float* __restrict__ EL,
    float* __restrict__ ER, int n) {
    int t = threadIdx.x;
    int row0 = blk * 64;

    {
        int r = t >> 2;
        int gr = row0 + r;
        unsigned int rowbase = r * 256;
        unsigned int sw = (r & 7) << 4;
        if (XBF16) {
            unsigned int kb0 = (t & 3) * 64;
            const char* src = (const char*)Xv + (size_t)gr * 256 + kb0;
            #pragma unroll
            for (int i = 0; i < 4; ++i) {
                int4 v = (gr < n) ? *(const int4*)(src + i * 16)
                                  : make_int4(0, 0, 0, 0);
                *(int4*)((char*)xs + rowbase + ((kb0 + i * 16) ^ sw)) = v;
            }
        } else {
            int k0 = (t & 3) * 32;
            float4 f[8];
            if (gr < n) {
                const float4* p = (const float4*)((const float*)Xv + (size_t)gr * HF + k0);
                #pragma unroll
                for (int i = 0; i < 8; ++i) f[i] = p[i];
            } else {
                #pragma unroll
                for (int i = 0; i < 8; ++i) f[i] = make_float4(0.f, 0.f, 0.f, 0.f);
            }
            #pragma unroll
            for (int g2 = 0; g2 < 4; ++g2) {
                float4 a = f[g2 * 2], b = f[g2 * 2 + 1];
                int4 pk;
                pk.x = (int)(f2bf(a.x) | (f2bf(a.y) << 16));
                pk.y = (int)(f2bf(a.z) | (f2bf(a.w) << 16));
                pk.z = (int)(f2bf(b.x) | (f2bf(b.y) << 16));
                pk.w = (int)(f2bf(b.z) | (f2bf(b.w) << 16));
                unsigned int addr = rowbase + ((unsigned)((k0 + g2 * 8) * 2) ^ sw);
                *(int4*)((char*)xs + addr) = pk;
            }
        }
    }
    {
        int c = t >> 1;
        unsigned int kb0 = (t & 1) * 128;
        const int4* src = (const int4*)((const char*)Wtb + (size_t)c * 256 + kb0);
        unsigned int sw = (c & 7) << 4;
        #pragma unroll
        for (int i = 0; i < 8; ++i) {
            int4 v = src[i];
            unsigned int addr = c * 256 + ((kb0 + i * 16) ^ sw);
            *(int4*)((char*)ws + addr) = v;
        }
    }
    __syncthreads();

    int wv = t >> 6;
    int l = t & 63;
    int lr = l & 15;
    int g = l >> 4;

    bf16x8 bfr[4];
    {
        int r = wv * 16 + lr;
        unsigned int rowbase = r * 256;
        unsigned int sw = (r & 7) << 4;
        #pragma unroll
        for (int s = 0; s < 4; ++s) {
            unsigned int kbyte = (unsigned)((s * 32 + g * 8) * 2);
            bfr[s] = *(bf16x8*)((char*)xs + rowbase + (kbyte ^ sw));
        }
    }

    f32x4 acc[8];
    #pragma unroll
    for (int ct = 0; ct < 8; ++ct) acc[ct] = (f32x4){0.f, 0.f, 0.f, 0.f};

    #pragma unroll
    for (int ct = 0; ct < 8; ++ct) {
        int c = ct * 16 + lr;
        unsigned int rowbase = c * 256;
        unsigned int sw = (c & 7) << 4;
        #pragma unroll
        for (int s = 0; s < 4; ++s) {
            unsigned int kbyte = (unsigned)((s * 32 + g * 8) * 2);
            bf16x8 af = *(bf16x8*)((char*)ws + rowbase + (kbyte ^ sw));
            acc[ct] = __builtin_amdgcn_mfma_f32_16x16x32_bf16(af, bfr[s], acc[ct], 0, 0, 0);
        }
    }

    int grow = row0 + wv * 16 + lr;
    bool valid = grow < n;

    if (valid) {
        #pragma unroll
        for (int ct = 0; ct < 8; ++ct) {
            ushort4 hb4 = make_ushort4(
                (unsigned short)f2bf(acc[ct][0]), (unsigned short)f2bf(acc[ct][1]),
                (unsigned short)f2bf(acc[ct][2]), (unsigned short)f2bf(acc[ct][3]));
            *(ushort4*)(Hb + (size_t)grow * HF + ct * 16 + g * 4) = hb4;
        }
    }

    #pragma unroll
    for (int ct = 0; ct < 8; ++ct) {
        float e1 = 0.f, e2 = 0.f;
        #pragma unroll
        for (int rg = 0; rg < 4; ++rg) {
            float alv = AL[ct * 16 + g * 4 + rg];
            float arv = AR[ct * 16 + g * 4 + rg];
            e1 += acc[ct][rg] * alv;
            e2 += acc[ct][rg] * arv;
        }
        e1 += __shfl_xor(e1, 16); e1 += __shfl_xor(e1, 32);
        e2 += __shfl_xor(e2, 16); e2 += __shfl_xor(e2, 32);
        if (g == 0 && valid) {
            EL[grow * HEADS + ct] = e1;
            ER[grow * HEADS + ct] = e2;
        }
    }
}

// -------------------- wtrans body (device inline, 256 thr) -----------------

static __device__ __forceinline__ void wtrans_body(
    int blk, const float* __restrict__ W, unsigned short* __restrict__ Wtb) {
    int gid = blk * 256 + threadIdx.x;
    int c = gid >> 3;
    int k0 = (gid & 7) * 16;
    #pragma unroll
    for (int q = 0; q < 4; ++q) {
        int k = k0 + q * 4;
        ushort4 o = make_ushort4(
            (unsigned short)f2bf(W[(k + 0) * HF + c]),
            (unsigned short)f2bf(W[(k + 1) * HF + c]),
            (unsigned short)f2bf(W[(k + 2) * HF + c]),
            (unsigned short)f2bf(W[(k + 3) * HF + c]));
        *(ushort4*)(Wtb + (size_t)c * HF + k) = o;
    }
}

// ------------------ csr body (device inline, 256 thr) ----------------------

static __device__ __forceinline__ void csr_body(
    int b, char* ldsc, const int* __restrict__ stage, const int* __restrict__ btot,
    int* __restrict__ rowptr, unsigned short* __restrict__ col,
    int N, int nb, int E) {
    int* hist  = (int*)ldsc;          // 256
    int* lscan = hist + 256;          // 256
    int* lcur  = lscan + 256;         // 256
    int* sb    = lcur + 256;          // 256
    int t = threadIdx.x;
    sb[t] = (t < nb) ? btot[t] : 0;
    hist[t] = 0;
    __syncthreads();
    #pragma unroll
    for (int off = 1; off < 256; off <<= 1) {
        int v = (t >= off) ? sb[t - off] : 0;
        __syncthreads();
        sb[t] += v;
        __syncthreads();
    }
    int e0 = (b == 0) ? 0 : sb[b - 1];
    int e1 = sb[b];
    if (b == 0 && t == 0) rowptr[N] = E;

    for (int i = e0 + t; i < e1; i += 256)
        atomicAdd(&hist[(stage[i] >> 16) & (BRANGE - 1)], 1);
    __syncthreads();
    lscan[t] = hist[t];
    __syncthreads();
    #pragma unroll
    for (int off = 1; off < 256; off <<= 1) {
        int v = (t >= off) ? lscan[t - off] : 0;
        __syncthreads();
        lscan[t] += v;
        __syncthreads();
    }
    int ex = (t == 0) ? 0 : lscan[t - 1];
    __syncthreads();
    lcur[t] = ex;
    int node = (b << BSHIFT) + t;
    if (node < N) rowptr[node] = e0 + ex;
    __syncthreads();
    for (int i = e0 + t; i < e1; i += 256) {
        int p = stage[i];
        int pos = e0 + atomicAdd(&lcur[(p >> 16) & (BRANGE - 1)], 1);
        col[pos] = (unsigned short)(p & 0xFFFF);
    }
}

// ---------------- fused_pre: bhist || wtrans(W0) || wtrans(W1) -------------

__global__ __launch_bounds__(256) void fused_pre_kernel(
    const int* __restrict__ edst, int* __restrict__ bhistT, int E, int nb, int nblk,
    const float* __restrict__ W0, unsigned short* __restrict__ wtb0,
    const float* __restrict__ W1, unsigned short* __restrict__ wtb1) {
    __shared__ int h[BRANGE];
    int b = blockIdx.x;
    int t = threadIdx.x;
    if (b < nblk) {
        h[t] = 0;
        __syncthreads();
        int base = b * CHUNK;
        int end = base + CHUNK; if (end > E) end = E;
        for (int i = base + t; i < end; i += 256)
            atomicAdd(&h[edst[i] >> BSHIFT], 1);
        __syncthreads();
        if (t < nb) bhistT[(size_t)t * nblk + b] = h[t];
    } else if (b < nblk + 4) {
        wtrans_body(b - nblk, W0, wtb0);
    } else {
        wtrans_body(b - nblk - 4, W1, wtb1);
    }
}

// per bucket: exclusive scan over blocks -> boffT[bucket][block]; total -> btot
__global__ __launch_bounds__(64) void bscan1_kernel(
    const int* __restrict__ bhistT, int* __restrict__ boffT,
    int* __restrict__ btot, int nblk) {
    int b = blockIdx.x;
    int l = threadIdx.x;
    int carry = 0;
    for (int c0 = 0; c0 < nblk; c0 += 64) {
        int blk = c0 + l;
        int v = (blk < nblk) ? bhistT[(size_t)b * nblk + blk] : 0;
        int x = v;
        #pragma unroll
        for (int off = 1; off < 64; off <<= 1) {
            int y = __shfl_up(x, off, 64);
            if (l >= off) x += y;
        }
        if (blk < nblk) boffT[(size_t)b * nblk + blk] = carry + x - v;
        carry += __shfl(x, 63);
    }
    if (l == 0) btot[b] = carry;
}

// bucket-group edges into stage; bucket bases derived in-LDS from btot
__global__ __launch_bounds__(512) void bucket_scatter_kernel(
    const int* __restrict__ src, const int* __restrict__ dst,
    const int* __restrict__ bhistT, const int* __restrict__ boffT,
    const int* __restrict__ btot, int* __restrict__ stage,
    int E, int nb, int nblk) {
    __shared__ int lscan[BRANGE];
    __shared__ int lcur[BRANGE];
    __shared__ int gbase[BRANGE];
    __shared__ int sb[BRANGE];
    __shared__ int sstage[CHUNK];
    int t = threadIdx.x;
    int blk = blockIdx.x;
    int base = blk * CHUNK;
    int end = base + CHUNK; if (end > E) end = E;

    if (t < 256) {
        lscan[t] = (t < nb) ? bhistT[(size_t)t * nblk + blk] : 0;
        sb[t] = (t < nb) ? btot[t] : 0;
    }
    __syncthreads();
    #pragma unroll
    for (int off = 1; off < 256; off <<= 1) {
        int v = 0, u = 0;
        if (t < 256 && t >= off) { v = lscan[t - off]; u = sb[t - off]; }
        __syncthreads();
        if (t < 256) { lscan[t] += v; sb[t] += u; }
        __syncthreads();
    }
    int ex = 0;
    if (t < 256) ex = (t == 0) ? 0 : lscan[t - 1];
    __syncthreads();
    if (t < 256) {
        lcur[t] = ex;
        lscan[t] = ex;
        if (t < nb) {
            int bb = (t == 0) ? 0 : sb[t - 1];
            gbase[t] = bb + boffT[(size_t)t * nblk + blk];
        }
    }
    __syncthreads();

    for (int i = base + t; i < end; i += 512) {
        int d = dst[i];
        int b = d >> BSHIFT;
        int pos = atomicAdd(&lcur[b], 1);
        sstage[pos] = (src[i] & 0xFFFF) | ((d & (BRANGE - 1)) << 16) | (b << 24);
    }
    __syncthreads();

    int total = end - base;
    for (int i = t; i < total; i += 512) {
        int p = sstage[i];
        int b = ((unsigned)p) >> 24;
        int gpos = gbase[b] + (i - lscan[b]);
        stage[gpos] = p;
    }
}

// ---------------- fused_mid: bucket_csr || gemm0 ---------------------------
// blocks [0,nCsr): csr (needs stage+btot); [nCsr, nCsr+gGemm): gemm layer 0.

__global__ __launch_bounds__(256) void fused_mid_kernel(
    const int* __restrict__ stage, const int* __restrict__ btot,
    int* __restrict__ rowptr, unsigned short* __restrict__ col,
    int N, int nb, int E, int nCsr,
    const float* __restrict__ X, const unsigned short* __restrict__ wtb0,
    const float* __restrict__ AL, const float* __restrict__ AR,
    unsigned short* __restrict__ Hb, float* __restrict__ EL,
    float* __restrict__ ER) {
    __shared__ __align__(16) unsigned char lds[48 * 1024];
    int b = blockIdx.x;
    if (b < nCsr) {
        csr_body(b, (char*)lds, stage, btot, rowptr, col, N, nb, E);
    } else {
        gemm_body<false>(b - nCsr, (unsigned short*)lds,
                         (unsigned short*)(lds + 16384),
                         X, wtb0, AL, AR, Hb, EL, ER, N);
    }
}

// ------------------------- standalone gemm (layer 1) -----------------------

template <bool XBF16>
__global__ __launch_bounds__(256) void gemm_mfma_kernel(
    const void* __restrict__ Xv, const unsigned short* __restrict__ Wtb,
    const float* __restrict__ AL, const float* __restrict__ AR,
    unsigned short* __restrict__ Hb, float* __restrict__ EL,
    float* __restrict__ ER, int n) {
    __shared__ __align__(16) unsigned short xs[64 * HF];
    __shared__ __align__(16) unsigned short ws[HF * HF];
    gemm_body<XBF16>(blockIdx.x, xs, ws, Xv, Wtb, AL, AR, Hb, EL, ER, n);
}

// --------------------------- softmax-aggregate ------------------------------

template <bool OBF16>
__global__ __launch_bounds__(256) void gat_aggregate_kernel(
    const unsigned int* __restrict__ HbU,   // bf16x2 view of Hb: [N][64]
    const float* __restrict__ EL, const float* __restrict__ ER,
    const int* __restrict__ rowptr, const unsigned short* __restrict__ col,
    void* __restrict__ OUT, int n) {
    int wid = (int)((blockIdx.x * blockDim.x + threadIdx.x) >> 6);
    if (wid >= n) return;
    int lane = threadIdx.x & 63;
    int s0 = rowptr[wid], s1 = rowptr[wid + 1];
    if (s1 == s0) {
        if (OBF16) ((unsigned int*)OUT)[(size_t)wid * 64 + lane] = 0u;
        else ((float2*)OUT)[(size_t)wid * 64 + lane] = make_float2(0.f, 0.f);
        return;
    }

    int h = lane & 7;
    int j = lane >> 3;
    int hC = lane >> 3;
    float er_h = ER[wid * HEADS + h];

    float accx = 0.f, accy = 0.f;
    float dpart = 0.f;

    for (int base = s0; base < s1; base += 8) {
        int i = base + j;
        int icl = i < s1 ? i : s1 - 1;
        int sj = (int)col[icl];
        float e = EL[sj * HEADS + h] + er_h;
        e = fmaxf(e, SLOPE * e);
        float w = __expf(e);
        if (i >= s1) w = 0.f;
        dpart += w;

        if (base + 8 <= s1) {
            #pragma unroll
            for (int jj = 0; jj < 8; ++jj) {
                float wC = __shfl(w, jj * 8 + hC);
                int s = __builtin_amdgcn_readlane(sj, jj * 8);
                unsigned int pv = HbU[(size_t)s * 64 + lane];
                accx += wC * __uint_as_float(pv << 16);
                accy += wC * __uint_as_float(pv & 0xffff0000u);
            }
        } else {
            int ne = s1 - base;
            for (int jj = 0; jj < ne; ++jj) {
                float wC = __shfl(w, jj * 8 + hC);
                int s = __builtin_amdgcn_readlane(sj, jj * 8);
                unsigned int pv = HbU[(size_t)s * 64 + lane];
                accx += wC * __uint_as_float(pv << 16);
                accy += wC * __uint_as_float(pv & 0xffff0000u);
            }
        }
    }

    dpart += __shfl_xor(dpart, 8);
    dpart += __shfl_xor(dpart, 16);
    dpart += __shfl_xor(dpart, 32);
    float rC = 1.f / __shfl(dpart, hC);

    if (OBF16) {
        unsigned int o = f2bf(accx * rC) | (f2bf(accy * rC) << 16);
        ((unsigned int*)OUT)[(size_t)wid * 64 + lane] = o;
    } else {
        ((float2*)OUT)[(size_t)wid * 64 + lane] = make_float2(accx * rC, accy * rC);
    }
}

// ------------------------------- launch -------------------------------------

extern "C" void kernel_launch(void* const* d_in, const int* in_sizes, int n_in,
                              void* d_out, int out_size, void* d_ws, size_t ws_size,
                              hipStream_t stream) {
    const float* feat = (const float*)d_in[0];
    const int*   esrc = (const int*)d_in[1];
    const int*   edst = (const int*)d_in[2];
    const float* W0   = (const float*)d_in[3];
    const float* al0  = (const float*)d_in[4];
    const float* ar0  = (const float*)d_in[5];
    const float* W1   = (const float*)d_in[6];
    const float* al1  = (const float*)d_in[7];
    const float* ar1  = (const float*)d_in[8];
    float* out = (float*)d_out;

    const int N = in_sizes[0] / HF;     // 50000
    const int E = in_sizes[1];          // 1600000
    const int nb = (N + BRANGE - 1) >> BSHIFT;        // 196
    const int nblk = (E + CHUNK - 1) / CHUNK;         // 391

    char* w = (char*)d_ws;
    auto alloc = [&](size_t bytes) -> void* {
        void* p = (void*)w;
        w += (bytes + 255) & ~(size_t)255;
        return p;
    };
    unsigned short* hb   = (unsigned short*)alloc((size_t)N * HF * 2);  // bf16 H
    unsigned short* x1b  = (unsigned short*)alloc((size_t)N * HF * 2);  // bf16 x1
    float* el_buf = (float*)alloc((size_t)N * HEADS * 4);
    float* er_buf = (float*)alloc((size_t)N * HEADS * 4);
    int*   rowptr = (int*)alloc((size_t)(N + 1) * 4);
    unsigned short* col = (unsigned short*)alloc((size_t)E * 2);
    int*   bhistT = (int*)alloc((size_t)nb * nblk * 4);
    int*   boffT  = (int*)alloc((size_t)nb * nblk * 4);
    int*   btot   = (int*)alloc((size_t)nb * 4);
    unsigned short* wtb0 = (unsigned short*)alloc((size_t)HF * HF * 2);
    unsigned short* wtb1 = (unsigned short*)alloc((size_t)HF * HF * 2);
    int*   stage  = (int*)alloc((size_t)E * 4);

    int gGemm = (N + 63) / 64;          // 782
    int gAgg  = (N * 64 + 255) / 256;

    // ---- fused_pre: bhist || wtrans(W0) || wtrans(W1) ----
    fused_pre_kernel<<<nblk + 8, 256, 0, stream>>>(edst, bhistT, E, nb, nblk,
                                                   W0, wtb0, W1, wtb1);
    // ---- per-bucket offsets ----
    bscan1_kernel<<<nb, 64, 0, stream>>>(bhistT, boffT, btot, nblk);
    // ---- bucket-group edges ----
    bucket_scatter_kernel<<<nblk, 512, 0, stream>>>(esrc, edst, bhistT, boffT,
                                                    btot, stage, E, nb, nblk);
    // ---- fused_mid: csr || gemm0 ----
    fused_mid_kernel<<<nb + gGemm, 256, 0, stream>>>(
        stage, btot, rowptr, col, N, nb, E, nb,
        feat, wtb0, al0, ar0, hb, el_buf, er_buf);

    // ---- layer 0 aggregate ----
    gat_aggregate_kernel<true><<<gAgg, 256, 0, stream>>>(
        (const unsigned int*)hb, el_buf, er_buf, rowptr, col, x1b, N);

    // ---- layer 1 ----
    gemm_mfma_kernel<true><<<gGemm, 256, 0, stream>>>(x1b, wtb1, al1, ar1,
                                                      hb, el_buf, er_buf, N);
    gat_aggregate_kernel<false><<<gAgg, 256, 0, stream>>>(
        (const unsigned int*)hb, el_buf, er_buf, rowptr, col, out, N);
}